// Round 8
// baseline (131.395 us; speedup 1.0000x reference)
//
#include <hip/hip_runtime.h>

typedef __attribute__((ext_vector_type(8))) short bf16x8;   // 8 bf16 in 4 VGPRs
typedef __attribute__((ext_vector_type(4))) float f32x4;

#define BLK   256
#define NWAVE 4
#define NPT   16      // points per wave-tile
#define MAXB  1024    // 4 blocks/CU -> 16 waves/CU = 4 waves/SIMD at <=128 total regs

union U4 { uint4 u; bf16x8 v; };

// tanh(x) = 1 - 2/(exp(2x)+1); ~1 ulp, saturates correctly.
__device__ __forceinline__ float tanh_fast(float v) {
    float e = __builtin_amdgcn_exp2f(v * 2.8853900817779268f);
    float r = __builtin_amdgcn_rcpf(e + 1.0f);
    return fmaf(-2.0f, r, 1.0f);
}

// {bf16(a) in low16, bf16(b) in high16} (truncation) = one v_perm_b32.
__device__ __forceinline__ unsigned int packlohi(unsigned int a, unsigned int b) {
    return __builtin_amdgcn_perm(b, a, 0x07060302u);
}

// Split 8 fp32 into bf16 hi (truncate) + lo (residual) register fragments.
__device__ __forceinline__ void pack8(const float* v, bf16x8* hi, bf16x8* lo) {
    unsigned int hb[8], lb[8];
#pragma unroll
    for (int j = 0; j < 8; ++j) {
        const unsigned int bits = __float_as_uint(v[j]);
        const unsigned int h = bits & 0xffff0000u;
        hb[j] = h;
        lb[j] = __float_as_uint(v[j] - __uint_as_float(h));
    }
    U4 uh, ul;
    uh.u = make_uint4(packlohi(hb[0],hb[1]), packlohi(hb[2],hb[3]),
                      packlohi(hb[4],hb[5]), packlohi(hb[6],hb[7]));
    ul.u = make_uint4(packlohi(lb[0],lb[1]), packlohi(lb[2],lb[3]),
                      packlohi(lb[4],lb[5]), packlohi(lb[6],lb[7]));
    *hi = uh.v;
    *lo = ul.v;
}

#define MFMA __builtin_amdgcn_mfma_f32_16x16x32_bf16

// Round-8: round-7 structure (A streamed from LDS, true live set ~110-122 regs)
// + __launch_bounds__(256, 4): forces the 128-reg cap (empirical: cap = 256/N)
// so NOTHING parks in AGPRs (no v_accvgpr copy VALU bloat) and 4 waves/SIMD
// become resident (grid = 4 blocks/CU). Round 6 proved the cap mechanism;
// round 7 proved the live-set reduction; this combines them.
// kappa(q,kc,j)=q*16+kc*8+j shared by A and B cancels in the contraction; B
// fragments are exactly what each lane computes in layer 1 for its own point.
// C/D: col=lane&15=p, row=(lane>>4)*4+reg -> h=m*16+q*4+r; epilogue lane-local.
__global__ __launch_bounds__(BLK, 4) void curl_mfma(
    const float* __restrict__ x,  const float* __restrict__ W1,
    const float* __restrict__ b1, const float* __restrict__ W2,
    const float* __restrict__ b2, const float* __restrict__ W3,
    float* __restrict__ out, int npts, int iters, int ntiles)
{
    // sA[((m*2+kc)*2+plane)*64 + lane]: packed A fragment (plane 0 = hi, 1 = lo).
    // Per-lane consecutive 16B -> conflict-free ds_read/ds_write.
    __shared__ uint4  sA[16 * 64];   // 16 KiB
    __shared__ float4 sW1[64];       // {W1[k,0..2], b1[k]}, slot-permuted — 1 KiB
    __shared__ float4 sLUT[64];      // {b2[h], W3[0][h], W3[1][h], W3[2][h]} — 1 KiB

    const int tid  = threadIdx.x;
    const int wv   = tid >> 6;
    const int lane = tid & 63;
    const int p    = lane & 15;   // point-in-tile == B col == D col
    const int q    = lane >> 4;   // k-group (kappa) and h-subgroup of D

    if (tid < 64) {
        sLUT[tid] = make_float4(b2[tid], W3[tid], W3[64 + tid], W3[128 + tid]);
        sW1[((tid & 15) << 2) | (tid >> 4)] =
            make_float4(W1[tid * 3 + 0], W1[tid * 3 + 1], W1[tid * 3 + 2], b1[tid]);
    }

    // Wave wv builds the A fragments for m = wv (W2 row m*16+p, k = kappa(q,kc,j)).
    {
        const int m = wv;
#pragma unroll
        for (int kc = 0; kc < 2; ++kc) {
            const float* src = W2 + (m * 16 + p) * 64 + q * 16 + kc * 8;
            const float4 va = ((const float4*)src)[0];
            const float4 vb = ((const float4*)src)[1];
            const float vv[8] = {va.x, va.y, va.z, va.w, vb.x, vb.y, vb.z, vb.w};
            bf16x8 hi, lo;
            pack8(vv, &hi, &lo);
            U4 uh, ul; uh.v = hi; ul.v = lo;
            sA[((m * 2 + kc) * 2 + 0) * 64 + lane] = uh.u;
            sA[((m * 2 + kc) * 2 + 1) * 64 + lane] = ul.u;
        }
    }
    __syncthreads();   // tables ready; no barriers after this point

    const int gw = blockIdx.x * NWAVE + wv;
    const int nw = gridDim.x * NWAVE;

    for (int it = 0; it < iters; ++it) {
        const int tile = gw + it * nw;
        if (tile >= ntiles) break;         // no barriers -> divergent exit is safe
        const int id = tile * NPT + p;

        float x0 = 0.f, x1 = 0.f, x2 = 0.f;
        if (id < npts) {
            x0 = x[id * 3 + 0];
            x1 = x[id * 3 + 1];
            x2 = x[id * 3 + 2];
        }

        // ---- Layer 1 + g = D1*W1col; pack straight into B register fragments ----
        bf16x8 Bhi[4][2], Blo[4][2];       // [type][kc] — 64 VGPRs, live all tile
#pragma unroll
        for (int kc = 0; kc < 2; ++kc) {
            float vh[8], v0[8], v1[8], v2[8];
#pragma unroll
            for (int j = 0; j < 8; ++j) {
                const float4 w = sW1[(((kc * 8 + j) & 15) << 2) | q];  // k=q*16+kc*8+j
                float a = fmaf(w.x, x0, w.w);
                a = fmaf(w.y, x1, a);
                a = fmaf(w.z, x2, a);
                const float th = tanh_fast(a);
                const float d1 = fmaf(-th, th, 1.0f);
                vh[j] = th;
                v0[j] = d1 * w.x;
                v1[j] = d1 * w.y;
                v2[j] = d1 * w.z;
            }
            pack8(vh, &Bhi[0][kc], &Blo[0][kc]);
            pack8(v0, &Bhi[1][kc], &Blo[1][kc]);
            pack8(v1, &Bhi[2][kc], &Blo[2][kc]);
            pack8(v2, &Bhi[3][kc], &Blo[3][kc]);
        }

        // ---- MFMA: m streamed from LDS (16 A-regs live), 24 MFMA per m ----
        float c0 = 0.f, c1 = 0.f, c2 = 0.f;
#pragma unroll 1
        for (int m = 0; m < 4; ++m) {
            U4 Ah0, Al0, Ah1, Al1;                   // A for this m only
            const uint4* pA = &sA[(m * 4) * 64 + lane];
            Ah0.u = pA[0 * 64];                      // kc0 hi
            Al0.u = pA[1 * 64];                      // kc0 lo
            Ah1.u = pA[2 * 64];                      // kc1 hi
            Al1.u = pA[3 * 64];                      // kc1 lo

            f32x4 a0 = {0.f,0.f,0.f,0.f}, a1 = a0, a2 = a0, a3 = a0;
            // kc = 0
            a0 = MFMA(Ah0.v, Bhi[0][0], a0, 0, 0, 0);
            a1 = MFMA(Ah0.v, Bhi[1][0], a1, 0, 0, 0);
            a2 = MFMA(Ah0.v, Bhi[2][0], a2, 0, 0, 0);
            a3 = MFMA(Ah0.v, Bhi[3][0], a3, 0, 0, 0);
            a0 = MFMA(Ah0.v, Blo[0][0], a0, 0, 0, 0);
            a1 = MFMA(Ah0.v, Blo[1][0], a1, 0, 0, 0);
            a2 = MFMA(Ah0.v, Blo[2][0], a2, 0, 0, 0);
            a3 = MFMA(Ah0.v, Blo[3][0], a3, 0, 0, 0);
            a0 = MFMA(Al0.v, Bhi[0][0], a0, 0, 0, 0);
            a1 = MFMA(Al0.v, Bhi[1][0], a1, 0, 0, 0);
            a2 = MFMA(Al0.v, Bhi[2][0], a2, 0, 0, 0);
            a3 = MFMA(Al0.v, Bhi[3][0], a3, 0, 0, 0);
            // kc = 1
            a0 = MFMA(Ah1.v, Bhi[0][1], a0, 0, 0, 0);
            a1 = MFMA(Ah1.v, Bhi[1][1], a1, 0, 0, 0);
            a2 = MFMA(Ah1.v, Bhi[2][1], a2, 0, 0, 0);
            a3 = MFMA(Ah1.v, Bhi[3][1], a3, 0, 0, 0);
            a0 = MFMA(Ah1.v, Blo[0][1], a0, 0, 0, 0);
            a1 = MFMA(Ah1.v, Blo[1][1], a1, 0, 0, 0);
            a2 = MFMA(Ah1.v, Blo[2][1], a2, 0, 0, 0);
            a3 = MFMA(Ah1.v, Blo[3][1], a3, 0, 0, 0);
            a0 = MFMA(Al1.v, Bhi[0][1], a0, 0, 0, 0);
            a1 = MFMA(Al1.v, Bhi[1][1], a1, 0, 0, 0);
            a2 = MFMA(Al1.v, Bhi[2][1], a2, 0, 0, 0);
            a3 = MFMA(Al1.v, Bhi[3][1], a3, 0, 0, 0);

            // Epilogue for h = m*16 + q*4 + r (a0=s0pre, a1=u0, a2=u1, a3=u2)
#pragma unroll
            for (int r = 0; r < 4; ++r) {
                const float4 lut = sLUT[m * 16 + q * 4 + r];
                const float s0 = a0[r] + lut.x;
                const float th = tanh_fast(s0);
                const float d2 = fmaf(-th, th, 1.0f);
                const float e0 = lut.y * d2, e1 = lut.z * d2, e2 = lut.w * d2;
                c0 = fmaf(e2, a2[r], c0); c0 = fmaf(-e1, a3[r], c0);
                c1 = fmaf(e0, a3[r], c1); c1 = fmaf(-e2, a1[r], c1);
                c2 = fmaf(e1, a1[r], c2); c2 = fmaf(-e0, a2[r], c2);
            }
        }

        // Reduce partial curls over the 4 h-subgroups (q dimension).
        c0 += __shfl_xor(c0, 16); c0 += __shfl_xor(c0, 32);
        c1 += __shfl_xor(c1, 16); c1 += __shfl_xor(c1, 32);
        c2 += __shfl_xor(c2, 16); c2 += __shfl_xor(c2, 32);

        // Coalesced store: lane (p,q<3) writes component q of point p ->
        // 48 contiguous dwords per tile.
        if (q < 3 && id < npts) {
            const float cv = (q == 0) ? c0 : ((q == 1) ? c1 : c2);
            out[tile * (NPT * 3) + p * 3 + q] = cv;
        }
    }
}

extern "C" void kernel_launch(void* const* d_in, const int* in_sizes, int n_in,
                              void* d_out, int out_size, void* d_ws, size_t ws_size,
                              hipStream_t stream) {
    const float* x  = (const float*)d_in[0];
    const float* W1 = (const float*)d_in[1];
    const float* b1 = (const float*)d_in[2];
    const float* W2 = (const float*)d_in[3];
    const float* b2 = (const float*)d_in[4];
    const float* W3 = (const float*)d_in[5];
    // d_in[6] (b3) unused: it cancels in the Jacobian.
    float* out = (float*)d_out;

    const int npts   = in_sizes[0] / 3;
    const int ntiles = (npts + NPT - 1) / NPT;
    int blocks = (ntiles + NWAVE - 1) / NWAVE;
    if (blocks > MAXB) blocks = MAXB;
    const int nw    = blocks * NWAVE;
    const int iters = (ntiles + nw - 1) / nw;

    hipLaunchKernelGGL(curl_mfma, dim3(blocks), dim3(BLK), 0, stream,
                       x, W1, b1, W2, b2, W3, out, npts, iters, ntiles);
}

// Round 11
// 108.272 us; speedup vs baseline: 1.2136x; 1.2136x over previous
//
#include <hip/hip_runtime.h>

typedef __attribute__((ext_vector_type(8))) _Float16 f16x8;  // 8 f16 in 4 VGPRs
typedef __attribute__((ext_vector_type(2))) __fp16 fp16x2r;  // cvt_pkrtz return type
typedef __attribute__((ext_vector_type(4))) float f32x4;

#define BLK   256
#define NWAVE 4
#define NPT   16      // points per wave-tile
#define MAXB  2048    // 8 blocks/CU -> residency limited by regs, not grid

union F16U { uint4 u; f16x8 v; };

// tanh(x) = 1 - 2/(exp(2x)+1); ~1 ulp, saturates correctly.
__device__ __forceinline__ float tanh_fast(float v) {
    float e = __builtin_amdgcn_exp2f(v * 2.8853900817779268f);
    float r = __builtin_amdgcn_rcpf(e + 1.0f);
    return fmaf(-2.0f, r, 1.0f);
}

// Two f32 -> packed f16x2 in one v_cvt_pkrtz_f16_f32.
__device__ __forceinline__ unsigned int pkh(float a, float b) {
    union { fp16x2r h; unsigned int u; } t;
    t.h = __builtin_amdgcn_cvt_pkrtz(a, b);
    return t.u;
}

// 8 f32 -> one f16x8 fragment: 4 VALU ops total (was 24 for the bf16 hi/lo pack).
__device__ __forceinline__ f16x8 pack8h(const float* v) {
    F16U r;
    r.u = make_uint4(pkh(v[0], v[1]), pkh(v[2], v[3]),
                     pkh(v[4], v[5]), pkh(v[6], v[7]));
    return r.v;
}

#define MFMA __builtin_amdgcn_mfma_f32_16x16x32_f16

// Round-11 = round-10 resubmitted (GPU acquisition timeout; kernel never ran).
// SINGLE-TERM FP16 MFMA. Rounds 5/7/8 all hit the same 76.5 us wall at
// different occupancies -> issue-port-bound (VALUBusy 63% + MfmaUtil 28% ~= 91%).
// The bf16 hi/lo 3-term split was 2/3 of the MFMA issue and ~190 VALU/tile of
// packing; f16 (11-bit mantissa) single-term cuts MFMA 96->32 and pack ops 6x
// via v_cvt_pkrtz. Error ~1e-3 abs vs observed passing absmax 0.0078.
// kappa(q,kc,j)=q*16+kc*8+j shared by A and B cancels in the contraction; B
// fragments are exactly what each lane computes in layer 1 for its own point.
// C/D: col=lane&15=p, row=(lane>>4)*4+reg -> h=m*16+q*4+r; epilogue lane-local.
__global__ __launch_bounds__(BLK, 2) void curl_mfma(
    const float* __restrict__ x,  const float* __restrict__ W1,
    const float* __restrict__ b1, const float* __restrict__ W2,
    const float* __restrict__ b2, const float* __restrict__ W3,
    float* __restrict__ out, int npts, int iters, int ntiles)
{
    // sA[(m*2+kc)*64 + lane]: packed f16 A fragment. Per-lane 16B -> conflict-free.
    __shared__ uint4  sA[8 * 64];    // 8 KiB
    __shared__ float4 sW1[64];       // {W1[k,0..2], b1[k]}, slot-permuted — 1 KiB
    __shared__ float4 sLUT[64];      // {b2[h], W3[0][h], W3[1][h], W3[2][h]} — 1 KiB

    const int tid  = threadIdx.x;
    const int wv   = tid >> 6;
    const int lane = tid & 63;
    const int p    = lane & 15;   // point-in-tile == B col == D col
    const int q    = lane >> 4;   // k-group (kappa) and h-subgroup of D

    if (tid < 64) {
        sLUT[tid] = make_float4(b2[tid], W3[tid], W3[64 + tid], W3[128 + tid]);
        sW1[((tid & 15) << 2) | (tid >> 4)] =
            make_float4(W1[tid * 3 + 0], W1[tid * 3 + 1], W1[tid * 3 + 2], b1[tid]);
    }

    // Wave wv builds the A fragments for m = wv (W2 row m*16+p, k = kappa(q,kc,j)).
    {
        const int m = wv;
#pragma unroll
        for (int kc = 0; kc < 2; ++kc) {
            const float* src = W2 + (m * 16 + p) * 64 + q * 16 + kc * 8;
            const float4 va = ((const float4*)src)[0];
            const float4 vb = ((const float4*)src)[1];
            const float vv[8] = {va.x, va.y, va.z, va.w, vb.x, vb.y, vb.z, vb.w};
            F16U uh; uh.v = pack8h(vv);
            sA[(m * 2 + kc) * 64 + lane] = uh.u;
        }
    }
    __syncthreads();   // tables ready; no barriers after this point

    const int gw = blockIdx.x * NWAVE + wv;
    const int nw = gridDim.x * NWAVE;

    for (int it = 0; it < iters; ++it) {
        const int tile = gw + it * nw;
        if (tile >= ntiles) break;         // no barriers -> divergent exit is safe
        const int id = tile * NPT + p;

        float x0 = 0.f, x1 = 0.f, x2 = 0.f;
        if (id < npts) {
            x0 = x[id * 3 + 0];
            x1 = x[id * 3 + 1];
            x2 = x[id * 3 + 2];
        }

        // ---- Layer 1 + g = D1*W1col; pack straight into f16 B fragments ----
        f16x8 Bf[4][2];                    // [type][kc] — 32 VGPRs
#pragma unroll
        for (int kc = 0; kc < 2; ++kc) {
            float vh[8], v0[8], v1[8], v2[8];
#pragma unroll
            for (int j = 0; j < 8; ++j) {
                const float4 w = sW1[(((kc * 8 + j) & 15) << 2) | q];  // k=q*16+kc*8+j
                float a = fmaf(w.x, x0, w.w);
                a = fmaf(w.y, x1, a);
                a = fmaf(w.z, x2, a);
                const float th = tanh_fast(a);
                const float d1 = fmaf(-th, th, 1.0f);
                vh[j] = th;
                v0[j] = d1 * w.x;
                v1[j] = d1 * w.y;
                v2[j] = d1 * w.z;
            }
            Bf[0][kc] = pack8h(vh);
            Bf[1][kc] = pack8h(v0);
            Bf[2][kc] = pack8h(v1);
            Bf[3][kc] = pack8h(v2);
        }

        // ---- MFMA: m streamed from LDS (8 A-regs live), 8 MFMA per m ----
        float c0 = 0.f, c1 = 0.f, c2 = 0.f;
#pragma unroll 1
        for (int m = 0; m < 4; ++m) {
            F16U A0, A1;                             // A for this m only
            const uint4* pA = &sA[(m * 2) * 64 + lane];
            A0.u = pA[0];                            // kc0
            A1.u = pA[64];                           // kc1

            f32x4 a0 = {0.f,0.f,0.f,0.f}, a1 = a0, a2 = a0, a3 = a0;
            a0 = MFMA(A0.v, Bf[0][0], a0, 0, 0, 0);
            a1 = MFMA(A0.v, Bf[1][0], a1, 0, 0, 0);
            a2 = MFMA(A0.v, Bf[2][0], a2, 0, 0, 0);
            a3 = MFMA(A0.v, Bf[3][0], a3, 0, 0, 0);
            a0 = MFMA(A1.v, Bf[0][1], a0, 0, 0, 0);
            a1 = MFMA(A1.v, Bf[1][1], a1, 0, 0, 0);
            a2 = MFMA(A1.v, Bf[2][1], a2, 0, 0, 0);
            a3 = MFMA(A1.v, Bf[3][1], a3, 0, 0, 0);

            // Epilogue for h = m*16 + q*4 + r (a0=s0pre, a1=u0, a2=u1, a3=u2)
#pragma unroll
            for (int r = 0; r < 4; ++r) {
                const float4 lut = sLUT[m * 16 + q * 4 + r];
                const float s0 = a0[r] + lut.x;
                const float th = tanh_fast(s0);
                const float d2 = fmaf(-th, th, 1.0f);
                const float e0 = lut.y * d2, e1 = lut.z * d2, e2 = lut.w * d2;
                c0 = fmaf(e2, a2[r], c0); c0 = fmaf(-e1, a3[r], c0);
                c1 = fmaf(e0, a3[r], c1); c1 = fmaf(-e2, a1[r], c1);
                c2 = fmaf(e1, a1[r], c2); c2 = fmaf(-e0, a2[r], c2);
            }
        }

        // Reduce partial curls over the 4 h-subgroups (q dimension).
        c0 += __shfl_xor(c0, 16); c0 += __shfl_xor(c0, 32);
        c1 += __shfl_xor(c1, 16); c1 += __shfl_xor(c1, 32);
        c2 += __shfl_xor(c2, 16); c2 += __shfl_xor(c2, 32);

        // Coalesced store: lane (p,q<3) writes component q of point p ->
        // 48 contiguous dwords per tile.
        if (q < 3 && id < npts) {
            const float cv = (q == 0) ? c0 : ((q == 1) ? c1 : c2);
            out[tile * (NPT * 3) + p * 3 + q] = cv;
        }
    }
}

extern "C" void kernel_launch(void* const* d_in, const int* in_sizes, int n_in,
                              void* d_out, int out_size, void* d_ws, size_t ws_size,
                              hipStream_t stream) {
    const float* x  = (const float*)d_in[0];
    const float* W1 = (const float*)d_in[1];
    const float* b1 = (const float*)d_in[2];
    const float* W2 = (const float*)d_in[3];
    const float* b2 = (const float*)d_in[4];
    const float* W3 = (const float*)d_in[5];
    // d_in[6] (b3) unused: it cancels in the Jacobian.
    float* out = (float*)d_out;

    const int npts   = in_sizes[0] / 3;
    const int ntiles = (npts + NPT - 1) / NPT;
    int blocks = (ntiles + NWAVE - 1) / NWAVE;
    if (blocks > MAXB) blocks = MAXB;
    const int nw    = blocks * NWAVE;
    const int iters = (ntiles + nw - 1) / nw;

    hipLaunchKernelGGL(curl_mfma, dim3(blocks), dim3(BLK), 0, stream,
                       x, W1, b1, W2, b2, W3, out, npts, iters, ntiles);
}

// Round 13
// 104.107 us; speedup vs baseline: 1.2621x; 1.0400x over previous
//
#include <hip/hip_runtime.h>

typedef __attribute__((ext_vector_type(8))) _Float16 f16x8;  // 8 f16 in 4 VGPRs
typedef __attribute__((ext_vector_type(2))) __fp16 fp16x2r;  // cvt_pkrtz return type
typedef __attribute__((ext_vector_type(4))) float f32x4;
typedef __attribute__((ext_vector_type(2))) float f32x2;

#define BLK   256
#define NWAVE 4
#define NPT   16      // points per wave-tile
#define MAXB  2048

union F16U  { uint4 u; f16x8 v; };
union PairU { float4 f4; f32x2 p[2]; };   // view float4 as two aligned f32 pairs
union AccU  { f32x4 v; f32x2 p[2]; };     // view MFMA acc as two aligned pairs

// ---- packed dual-FP32 via NATIVE vector ops (no inline asm; the compiler
// selects v_pk_fma_f32 / v_pk_mul_f32 / v_pk_add_f32 on gfx90a+ with correct
// op_sel encoding — round-12's hand asm produced garbage). ----
__device__ __forceinline__ f32x2 pk_fma(f32x2 a, f32x2 b, f32x2 c) {
    return __builtin_elementwise_fma(a, b, c);
}
__device__ __forceinline__ f32x2 pk_mul(f32x2 a, f32x2 b) { return a * b; }
__device__ __forceinline__ f32x2 pk_add(f32x2 a, f32x2 b) { return a + b; }

// Packed tanh pair: same formula (exp2/rcp ~1 ulp); trans ops stay scalar
// (no packed transcendental), all VALU glue is v2f32.
__device__ __forceinline__ f32x2 tanh2(f32x2 a, f32x2 cst2, f32x2 one2, f32x2 ntwo2) {
    f32x2 earg = pk_mul(a, cst2);
    f32x2 e;
    e.x = __builtin_amdgcn_exp2f(earg.x);
    e.y = __builtin_amdgcn_exp2f(earg.y);
    f32x2 ep1 = pk_add(e, one2);
    f32x2 r;
    r.x = __builtin_amdgcn_rcpf(ep1.x);
    r.y = __builtin_amdgcn_rcpf(ep1.y);
    return pk_fma(ntwo2, r, one2);     // 1 - 2/(e^2a+1)
}

// Two f32 -> packed f16x2 in one v_cvt_pkrtz_f16_f32.
__device__ __forceinline__ unsigned int pkh(float a, float b) {
    union { fp16x2r h; unsigned int u; } t;
    t.h = __builtin_amdgcn_cvt_pkrtz(a, b);
    return t.u;
}

__device__ __forceinline__ f16x8 pack8h(const float* v) {
    F16U r;
    r.u = make_uint4(pkh(v[0], v[1]), pkh(v[2], v[3]),
                     pkh(v[4], v[5]), pkh(v[6], v[7]));
    return r.v;
}

#define MFMA __builtin_amdgcn_mfma_f32_16x16x32_f16

// Round-13 = round-12 with the packed math re-expressed as native v2f32 ops
// (compiler-selected v_pk_*; r12's hand-written VOP3P asm returned garbage).
// Design: f16 single-term MFMA (r11, 49.4us, absmax 0.0078 vs threshold 0.0256)
// + pair-packed layer-1/epilogue to cut the saturated VALU issue ~25%.
// kappa(q,kc,j)=q*16+kc*8+j shared by A and B cancels in the contraction.
// C/D: col=lane&15=p, row=(lane>>4)*4+reg -> h=m*16+q*4+r; epilogue lane-local.
__global__ __launch_bounds__(BLK, 2) void curl_mfma(
    const float* __restrict__ x,  const float* __restrict__ W1,
    const float* __restrict__ b1, const float* __restrict__ W2,
    const float* __restrict__ b2, const float* __restrict__ W3,
    float* __restrict__ out, int npts, int iters, int ntiles)
{
    // sA[(m*2+kc)*64 + lane]: packed f16 A fragment. Per-lane 16B -> conflict-free.
    __shared__ uint4  sA[8 * 64];     // 8 KiB
    // Pair tables, slot-permuted so the 4 simultaneous q-addresses are 16B apart:
    // sW1xy[slot]={W1x[k0],W1x[k1],W1y[k0],W1y[k1]}, sW1zb={W1z pair, b1 pair},
    // slot = ((kc*4+u)<<2)|q for k pair (q*16+kc*8+2u, +1).
    __shared__ float4 sW1xy[32], sW1zb[32];   // 1 KiB
    // sLUTa[m*8+q*2+rp]={b2 pair, W3row0 pair}, sLUTb={W3row1 pair, W3row2 pair}
    // for h pair (m*16+q*4+2rp, +1); q-addresses 32B apart -> conflict-free.
    __shared__ float4 sLUTa[32], sLUTb[32];   // 1 KiB

    const int tid  = threadIdx.x;
    const int wv   = tid >> 6;
    const int lane = tid & 63;
    const int p    = lane & 15;   // point-in-tile == B col == D col
    const int q    = lane >> 4;   // k-group (kappa) and h-subgroup of D

    if (tid < 32) {
        // W1 pair tables: tid = qq*8 + kc*4 + u
        {
            const int qq = tid >> 3, kc = (tid >> 2) & 1, u = tid & 3;
            const int k0 = qq * 16 + kc * 8 + u * 2, k1 = k0 + 1;
            const int slot = ((kc * 4 + u) << 2) | qq;
            sW1xy[slot] = make_float4(W1[k0*3+0], W1[k1*3+0], W1[k0*3+1], W1[k1*3+1]);
            sW1zb[slot] = make_float4(W1[k0*3+2], W1[k1*3+2], b1[k0],     b1[k1]);
        }
        // LUT pair tables: tid = m*8 + qq*2 + rp
        {
            const int m = tid >> 3, qq = (tid >> 1) & 3, rp = tid & 1;
            const int h0 = m * 16 + qq * 4 + rp * 2, h1 = h0 + 1;
            sLUTa[tid] = make_float4(b2[h0], b2[h1], W3[h0], W3[h1]);
            sLUTb[tid] = make_float4(W3[64+h0], W3[64+h1], W3[128+h0], W3[128+h1]);
        }
    }

    // Wave wv builds the A fragments for m = wv (W2 row m*16+p, k = kappa(q,kc,j)).
    {
        const int m = wv;
#pragma unroll
        for (int kc = 0; kc < 2; ++kc) {
            const float* src = W2 + (m * 16 + p) * 64 + q * 16 + kc * 8;
            const float4 va = ((const float4*)src)[0];
            const float4 vb = ((const float4*)src)[1];
            const float vv[8] = {va.x, va.y, va.z, va.w, vb.x, vb.y, vb.z, vb.w};
            F16U uh; uh.v = pack8h(vv);
            sA[(m * 2 + kc) * 64 + lane] = uh.u;
        }
    }
    __syncthreads();   // tables ready; no barriers after this point

    // Loop-invariant packed constants.
    const f32x2 one2  = {1.0f, 1.0f};
    const f32x2 none2 = {-1.0f, -1.0f};
    const f32x2 ntwo2 = {-2.0f, -2.0f};
    const f32x2 cst2  = {2.8853900817779268f, 2.8853900817779268f};

    const int gw = blockIdx.x * NWAVE + wv;
    const int nw = gridDim.x * NWAVE;

    for (int it = 0; it < iters; ++it) {
        const int tile = gw + it * nw;
        if (tile >= ntiles) break;         // no barriers -> divergent exit is safe
        const int id = tile * NPT + p;

        float x0 = 0.f, x1 = 0.f, x2 = 0.f;
        if (id < npts) {
            x0 = x[id * 3 + 0];
            x1 = x[id * 3 + 1];
            x2 = x[id * 3 + 2];
        }
        const f32x2 x0_2 = {x0, x0}, x1_2 = {x1, x1}, x2_2 = {x2, x2};

        // ---- Layer 1 + g = D1*W1col, pair-packed; pack into f16 B fragments ----
        f16x8 Bf[4][2];                    // [type][kc] — 32 VGPRs
#pragma unroll
        for (int kc = 0; kc < 2; ++kc) {
            unsigned int wh[4], w0[4], w1[4], w2[4];
#pragma unroll
            for (int u = 0; u < 4; ++u) {
                PairU wxy, wzb;
                wxy.f4 = sW1xy[((kc * 4 + u) << 2) | q];
                wzb.f4 = sW1zb[((kc * 4 + u) << 2) | q];
                f32x2 a = pk_fma(wxy.p[0], x0_2, wzb.p[1]);   // W1x*x0 + b1
                a = pk_fma(wxy.p[1], x1_2, a);
                a = pk_fma(wzb.p[0], x2_2, a);
                const f32x2 th = tanh2(a, cst2, one2, ntwo2);
                const f32x2 t2 = pk_mul(th, th);
                const f32x2 d1 = pk_fma(t2, none2, one2);     // 1 - th^2
                const f32x2 g0 = pk_mul(d1, wxy.p[0]);
                const f32x2 g1 = pk_mul(d1, wxy.p[1]);
                const f32x2 g2 = pk_mul(d1, wzb.p[0]);
                wh[u] = pkh(th.x, th.y);
                w0[u] = pkh(g0.x, g0.y);
                w1[u] = pkh(g1.x, g1.y);
                w2[u] = pkh(g2.x, g2.y);
            }
            F16U t;
            t.u = make_uint4(wh[0], wh[1], wh[2], wh[3]); Bf[0][kc] = t.v;
            t.u = make_uint4(w0[0], w0[1], w0[2], w0[3]); Bf[1][kc] = t.v;
            t.u = make_uint4(w1[0], w1[1], w1[2], w1[3]); Bf[2][kc] = t.v;
            t.u = make_uint4(w2[0], w2[1], w2[2], w2[3]); Bf[3][kc] = t.v;
        }

        // ---- MFMA + pair-packed epilogue; curl via +/- accumulators ----
        f32x2 cp0 = {0.f,0.f}, cp1 = cp0, cp2 = cp0;
        f32x2 cn0 = cp0, cn1 = cp0, cn2 = cp0;
#pragma unroll 1
        for (int m = 0; m < 4; ++m) {
            F16U A0, A1;
            const uint4* pA = &sA[(m * 2) * 64 + lane];
            A0.u = pA[0];
            A1.u = pA[64];

            AccU a0, a1, a2, a3;
            a0.v = (f32x4){0.f,0.f,0.f,0.f}; a1.v = a0.v; a2.v = a0.v; a3.v = a0.v;
            a0.v = MFMA(A0.v, Bf[0][0], a0.v, 0, 0, 0);
            a1.v = MFMA(A0.v, Bf[1][0], a1.v, 0, 0, 0);
            a2.v = MFMA(A0.v, Bf[2][0], a2.v, 0, 0, 0);
            a3.v = MFMA(A0.v, Bf[3][0], a3.v, 0, 0, 0);
            a0.v = MFMA(A1.v, Bf[0][1], a0.v, 0, 0, 0);
            a1.v = MFMA(A1.v, Bf[1][1], a1.v, 0, 0, 0);
            a2.v = MFMA(A1.v, Bf[2][1], a2.v, 0, 0, 0);
            a3.v = MFMA(A1.v, Bf[3][1], a3.v, 0, 0, 0);

            // Epilogue pairs rp: h = m*16 + q*4 + {2rp, 2rp+1}
            // (a0=s0pre, a1=u0, a2=u1, a3=u2; acc pair rp is regs {2rp,2rp+1})
#pragma unroll
            for (int rp = 0; rp < 2; ++rp) {
                PairU la, lb;
                la.f4 = sLUTa[m * 8 + q * 2 + rp];
                lb.f4 = sLUTb[m * 8 + q * 2 + rp];
                const f32x2 s0 = pk_add(a0.p[rp], la.p[0]);
                const f32x2 th = tanh2(s0, cst2, one2, ntwo2);
                const f32x2 t2 = pk_mul(th, th);
                const f32x2 d2 = pk_fma(t2, none2, one2);
                const f32x2 e0 = pk_mul(la.p[1], d2);
                const f32x2 e1 = pk_mul(lb.p[0], d2);
                const f32x2 e2 = pk_mul(lb.p[1], d2);
                // c0 += e2*u1 - e1*u2 ; c1 += e0*u2 - e2*u0 ; c2 += e1*u0 - e0*u1
                cp0 = pk_fma(e2, a2.p[rp], cp0);  cn0 = pk_fma(e1, a3.p[rp], cn0);
                cp1 = pk_fma(e0, a3.p[rp], cp1);  cn1 = pk_fma(e2, a1.p[rp], cn1);
                cp2 = pk_fma(e1, a1.p[rp], cp2);  cn2 = pk_fma(e0, a2.p[rp], cn2);
            }
        }

        float c0 = (cp0.x - cn0.x) + (cp0.y - cn0.y);
        float c1 = (cp1.x - cn1.x) + (cp1.y - cn1.y);
        float c2 = (cp2.x - cn2.x) + (cp2.y - cn2.y);

        // Reduce partial curls over the 4 h-subgroups (q dimension).
        c0 += __shfl_xor(c0, 16); c0 += __shfl_xor(c0, 32);
        c1 += __shfl_xor(c1, 16); c1 += __shfl_xor(c1, 32);
        c2 += __shfl_xor(c2, 16); c2 += __shfl_xor(c2, 32);

        // Coalesced store: lane (p,q<3) writes component q of point p.
        if (q < 3 && id < npts) {
            const float cv = (q == 0) ? c0 : ((q == 1) ? c1 : c2);
            out[tile * (NPT * 3) + p * 3 + q] = cv;
        }
    }
}

extern "C" void kernel_launch(void* const* d_in, const int* in_sizes, int n_in,
                              void* d_out, int out_size, void* d_ws, size_t ws_size,
                              hipStream_t stream) {
    const float* x  = (const float*)d_in[0];
    const float* W1 = (const float*)d_in[1];
    const float* b1 = (const float*)d_in[2];
    const float* W2 = (const float*)d_in[3];
    const float* b2 = (const float*)d_in[4];
    const float* W3 = (const float*)d_in[5];
    // d_in[6] (b3) unused: it cancels in the Jacobian.
    float* out = (float*)d_out;

    const int npts   = in_sizes[0] / 3;
    const int ntiles = (npts + NPT - 1) / NPT;
    int blocks = (ntiles + NWAVE - 1) / NWAVE;
    if (blocks > MAXB) blocks = MAXB;
    const int nw    = blocks * NWAVE;
    const int iters = (ntiles + nw - 1) / nw;

    hipLaunchKernelGGL(curl_mfma, dim3(blocks), dim3(BLK), 0, stream,
                       x, W1, b1, W2, b2, W3, out, npts, iters, ntiles);
}